// Round 5
// baseline (361.737 us; speedup 1.0000x reference)
//
#include <hip/hip_runtime.h>

#define NB 16
#define NC 256
#define HW 2304
#define CHW 589824  // NC*HW

typedef __attribute__((ext_vector_type(8))) short bf16x8;
typedef __attribute__((ext_vector_type(16))) float f32x16;

union BF8 { bf16x8 v; unsigned short u[8]; };

__device__ inline unsigned short f2bf(float f) {
  unsigned u = __builtin_bit_cast(unsigned, f);
  u += 0x7fffu + ((u >> 16) & 1u);  // RNE (inputs finite)
  return (unsigned short)(u >> 16);
}

// ---------------- wpack: W (256x256 fp32) -> bf16 A-frags, once ----------------
// wp[rt][f][l][j] = W[32rt + (l&31)][16f + 8*(l>>5) + j]
__global__ __launch_bounds__(256) void wpack_kernel(const float* __restrict__ W,
                                                    unsigned short* __restrict__ wp) {
  const int rt = blockIdx.x;  // 8 row-tiles of 32
  const float4* src = (const float4*)(W + (size_t)rt * 32 * 256);
  __shared__ float tile[32 * 260];
  const int tid = threadIdx.x;
  #pragma unroll
  for (int it = 0; it < 8; ++it) {
    const int i = tid + 256 * it;
    float4 v = src[i];
    const int fi = 4 * i, row = fi >> 8, col = fi & 255;
    *(float4*)&tile[row * 260 + col] = v;
  }
  __syncthreads();
  const int w = tid >> 6, l = tid & 63, l31 = l & 31, h = l >> 5;
  unsigned short* dst = wp + (size_t)rt * 8192;
  #pragma unroll
  for (int ff = 0; ff < 4; ++ff) {
    const int f = 4 * w + ff;
    BF8 o;
    #pragma unroll
    for (int j = 0; j < 8; ++j)
      o.u[j] = f2bf(tile[l31 * 260 + 16 * f + 8 * h + j]);
    *(bf16x8*)(dst + (((size_t)f) * 64 + l) * 8) = o.v;
  }
}

// ---------------- x1pack: bf16 A-frags of X1 (flat view) + per-block sumsq ----------------
// x1p[b][nb][f][l][j] = v[(32nb + (l&31))*256 + 16f + 8*(l>>5) + j]
__global__ __launch_bounds__(256) void x1pack_kernel(const float* __restrict__ x,
                                                     unsigned short* __restrict__ x1p,
                                                     double* __restrict__ partials) {
  const int nb = blockIdx.x, b = blockIdx.y;
  const float4* src = (const float4*)(x + (size_t)b * CHW + nb * 8192);
  __shared__ float tile[32 * 260];
  __shared__ double red[4];
  const int tid = threadIdx.x;
  double ss = 0.0;
  #pragma unroll
  for (int it = 0; it < 8; ++it) {
    const int i = tid + 256 * it;
    float4 v = src[i];
    const int fi = 4 * i, row = fi >> 8, col = fi & 255;
    *(float4*)&tile[row * 260 + col] = v;
    ss += (double)v.x * v.x + (double)v.y * v.y + (double)v.z * v.z + (double)v.w * v.w;
  }
  #pragma unroll
  for (int off = 32; off > 0; off >>= 1) ss += __shfl_down(ss, off, 64);
  const int w = tid >> 6, l = tid & 63;
  if (l == 0) red[w] = ss;
  __syncthreads();
  if (tid == 0) partials[b * 72 + nb] = red[0] + red[1] + red[2] + red[3];
  const int l31 = l & 31, h = l >> 5;
  unsigned short* dst = x1p + (size_t)b * CHW + (size_t)nb * 8192;
  #pragma unroll
  for (int ff = 0; ff < 4; ++ff) {
    const int f = 4 * w + ff;
    BF8 o;
    #pragma unroll
    for (int j = 0; j < 8; ++j)
      o.u[j] = f2bf(tile[l31 * 260 + 16 * f + 8 * h + j]);
    *(bf16x8*)(dst + (((size_t)f) * 64 + l) * 8) = o.v;
  }
}

// ---------------- xtpack: bf16 B-frags of X2 (transposed view) ----------------
// xtp[b][mb][f][l][j] = x[b][k = 16f+8*(l>>5)+j][m = 32mb + (l&31)]
__global__ __launch_bounds__(256) void xtpack_kernel(const float* __restrict__ x,
                                                     unsigned short* __restrict__ xtp) {
  const int mt = blockIdx.x, kt = blockIdx.y, b = blockIdx.z;
  const int m0 = mt * 64, k0 = kt * 64;
  const float* xb = x + (size_t)b * CHW;
  __shared__ float tile[64 * 68];
  const int tid = threadIdx.x;
  #pragma unroll
  for (int it = 0; it < 4; ++it) {
    const int i = tid + 256 * it;
    const int row = i >> 4, c4 = (i & 15) * 4;
    float4 v = *(const float4*)(xb + (size_t)(k0 + row) * HW + m0 + c4);
    *(float4*)&tile[row * 68 + c4] = v;
  }
  __syncthreads();
  const int w = tid >> 6, l = tid & 63, l31 = l & 31, h = l >> 5;
  unsigned short* dst = xtp + (size_t)b * CHW;
  #pragma unroll
  for (int pp = 0; pp < 2; ++pp) {
    const int p = 2 * w + pp, mbl = p >> 2, fl = p & 3;
    BF8 o;
    #pragma unroll
    for (int j = 0; j < 8; ++j)
      o.u[j] = f2bf(tile[(16 * fl + 8 * h + j) * 68 + 32 * mbl + l31]);
    const int mb = 2 * mt + mbl, f = 4 * kt + fl;
    *(bf16x8*)(dst + (((size_t)mb * 16 + f) * 64 + l) * 8) = o.v;
  }
}

// ---------------- conv (MFMA): trflat[c'][m] = sum_k W[c'][k]*x[b][k][m] + bias[c'] ----------------
__global__ __launch_bounds__(256, 2) void conv_kernel(const unsigned short* __restrict__ wp,
                                                      const float* __restrict__ bias,
                                                      const unsigned short* __restrict__ xtp,
                                                      unsigned short* __restrict__ trflat) {
  const int bid = blockIdx.x;
  const int xcd = bid & 7, j = bid >> 3;
  const int hi = (j >= 36) ? 1 : 0;
  const int b = xcd + 8 * hi;
  const int ch = j - 36 * hi;
  const int m0 = ch * 64;
  const int tid = threadIdx.x, w = tid >> 6, l = tid & 63, l31 = l & 31, h = l >> 5;
  const unsigned short* xb = xtp + (size_t)b * CHW;
  unsigned short* tb = trflat + (size_t)b * CHW;
  bf16x8 af[2][16];
  #pragma unroll
  for (int rb = 0; rb < 2; ++rb) {
    const int rt = w + 4 * rb;
    #pragma unroll
    for (int f = 0; f < 16; ++f)
      af[rb][f] = *(const bf16x8*)(wp + (((size_t)rt * 16 + f) * 64 + l) * 8);
  }
  f32x16 yacc[2][2];
  #pragma unroll
  for (int rb = 0; rb < 2; ++rb)
    #pragma unroll
    for (int cb = 0; cb < 2; ++cb)
      #pragma unroll
      for (int i = 0; i < 16; ++i) yacc[rb][cb][i] = 0.f;
  #pragma unroll 4
  for (int f = 0; f < 16; ++f) {
    #pragma unroll
    for (int cb = 0; cb < 2; ++cb) {
      const int mb = 2 * ch + cb;
      bf16x8 bv = *(const bf16x8*)(xb + (((size_t)mb * 16 + f) * 64 + l) * 8);
      yacc[0][cb] = __builtin_amdgcn_mfma_f32_32x32x16_bf16(af[0][f], bv, yacc[0][cb], 0, 0, 0);
      yacc[1][cb] = __builtin_amdgcn_mfma_f32_32x32x16_bf16(af[1][f], bv, yacc[1][cb], 0, 0, 0);
    }
  }
  #pragma unroll
  for (int rb = 0; rb < 2; ++rb)
    #pragma unroll
    for (int reg = 0; reg < 16; ++reg) {
      const int row = 32 * (w + 4 * rb) + (reg & 3) + 8 * (reg >> 2) + 4 * h;
      const float bv = bias[row];
      #pragma unroll
      for (int cb = 0; cb < 2; ++cb)
        tb[(size_t)row * HW + m0 + 32 * cb + l31] = f2bf(yacc[rb][cb][reg] + bv);
    }
}

// ---------------- trpack: trflat -> B-frags of TR for Y GEMM ----------------
// trp[b][mb][cb8][kf][l][j] = trflat_flat[(64mb + 16kf + 8*(l>>5) + j)*256 + 32cb8 + (l&31)]
__global__ __launch_bounds__(256) void trpack_kernel(const unsigned short* __restrict__ trflat,
                                                     unsigned short* __restrict__ trp) {
  const int mb = blockIdx.x, half = blockIdx.y, b = blockIdx.z;
  const unsigned short* src = trflat + (size_t)b * CHW + (size_t)mb * 16384 + 128 * half;
  __shared__ unsigned short tile[64 * 136];
  const int tid = threadIdx.x;
  #pragma unroll
  for (int it = 0; it < 4; ++it) {
    const int i = tid + 256 * it;
    const int row = i >> 4, c8 = (i & 15) * 8;
    *(uint4*)&tile[row * 136 + c8] = *(const uint4*)(src + (size_t)row * 256 + c8);
  }
  __syncthreads();
  const int kf = tid >> 6, l = tid & 63, l31 = l & 31, h = l >> 5;
  unsigned short* dst = trp + (size_t)b * CHW + (size_t)mb * 16384;
  #pragma unroll
  for (int cl = 0; cl < 4; ++cl) {
    BF8 o;
    #pragma unroll
    for (int j = 0; j < 8; ++j)
      o.u[j] = tile[(16 * kf + 8 * h + j) * 136 + 32 * cl + l31];
    const int cb8 = 4 * half + cl;
    *(bf16x8*)(dst + (((size_t)cb8 * 4 + kf) * 64 + l) * 8) = o.v;
  }
}

// ---------------- fused: n=64 blocks, 2x2 waves, chunk m=64, reg A-frags ----------------
__global__ __launch_bounds__(256, 2) void fused_kernel(const unsigned short* __restrict__ x1p,
                                                       const unsigned short* __restrict__ xtp,
                                                       const unsigned short* __restrict__ trp,
                                                       const double* __restrict__ partials,
                                                       float* __restrict__ out) {
  const int bid = blockIdx.x;
  const int xcd = bid & 7, j = bid >> 3;      // j in [0,72)
  const int hi = (j >= 36) ? 1 : 0;
  const int b = xcd + 8 * hi;                 // one batch per XCD at a time
  const int nt = j - 36 * hi;                 // n-tile of 64 rows
  const unsigned short* x1b = x1p + (size_t)b * CHW;
  const unsigned short* xtb = xtp + (size_t)b * CHW;
  const unsigned short* ttb = trp + (size_t)b * CHW;
  float* ob = out + (size_t)b * CHW;

  const int tid = threadIdx.x;
  const int w = tid >> 6, lane = tid & 63;
  const int l31 = lane & 31, h = lane >> 5;
  const int rt = w >> 1, ct = w & 1;          // 2x2: row-tile, col-tile

  __shared__ unsigned short Pl[2][64][72];    // double-buffered P, pitch 144 B
  __shared__ double red[72];
  __shared__ float s_inv2;

  // prologue: reduce this batch's 72 sumsq partials -> 1/xn^2 (replaces finish kernel)
  if (tid < 72) red[tid] = partials[b * 72 + tid];
  __syncthreads();
  if (tid == 0) {
    double s = 0.0;
    for (int i = 0; i < 72; ++i) s += red[i];
    s_inv2 = (float)(1.0 / s);
  }

  // A-frags for this wave's 32 rows (x1p tile 2nt+rt), register-resident
  bf16x8 af[16];
  {
    const unsigned short* ap = x1b + (size_t)(2 * nt + rt) * 8192 + lane * 8;
    #pragma unroll
    for (int f = 0; f < 16; ++f) af[f] = *(const bf16x8*)(ap + f * 512);
  }

  f32x16 yacc[4];
  #pragma unroll
  for (int cb = 0; cb < 4; ++cb)
    #pragma unroll
    for (int i = 0; i < 16; ++i) yacc[cb][i] = 0.f;

  __syncthreads();
  const float inv2 = s_inv2;

  for (int ch = 0; ch < 36; ++ch) {
    const int pb = ch & 1;
    // ---- S phase: 16 coalesced B-frag loads + 16 MFMAs (two 8-chains) ----
    const unsigned short* bp = xtb + (size_t)(2 * ch + ct) * 8192 + lane * 8;
    f32x16 s0, s1;
    #pragma unroll
    for (int i = 0; i < 16; ++i) { s0[i] = 0.f; s1[i] = 0.f; }
    #pragma unroll
    for (int f = 0; f < 8; ++f) {
      bf16x8 bv = *(const bf16x8*)(bp + f * 512);
      s0 = __builtin_amdgcn_mfma_f32_32x32x16_bf16(af[f], bv, s0, 0, 0, 0);
    }
    #pragma unroll
    for (int f = 0; f < 8; ++f) {
      bf16x8 bv = *(const bf16x8*)(bp + (f + 8) * 512);
      s1 = __builtin_amdgcn_mfma_f32_32x32x16_bf16(af[f + 8], bv, s1, 0, 0, 0);
    }
    // ---- prefetch Y B-frags for col-tiles 0,1 (complete by barrier vmcnt drain) ----
    const unsigned short* tp = ttb + (size_t)ch * 16384 + lane * 8;
    bf16x8 bt0[8];
    #pragma unroll
    for (int q = 0; q < 8; ++q)
      bt0[q] = *(const bf16x8*)(tp + (size_t)((4 * ct + (q >> 2)) * 4 + (q & 3)) * 512);
    // ---- P = relu((s0+s1)*inv2)^2 -> bf16 -> LDS quadrant ----
    #pragma unroll
    for (int reg = 0; reg < 16; ++reg) {
      const int rowp = (reg & 3) + 8 * (reg >> 2) + 4 * h;
      float v = (s0[reg] + s1[reg]) * inv2;
      v = fmaxf(v, 0.f);
      v *= v;
      Pl[pb][32 * rt + rowp][32 * ct + l31] = f2bf(v);
    }
    __syncthreads();  // single barrier per chunk (double-buffered P)
    // ---- P A-frags (rows 32rt+l31, k = m-local) + remaining Y B-frags ----
    bf16x8 pf[4];
    #pragma unroll
    for (int kf = 0; kf < 4; ++kf)
      pf[kf] = *(const bf16x8*)&Pl[pb][32 * rt + l31][16 * kf + 8 * h];
    bf16x8 bt1[8];
    #pragma unroll
    for (int q = 0; q < 8; ++q)
      bt1[q] = *(const bf16x8*)(tp + (size_t)((4 * ct + 2 + (q >> 2)) * 4 + (q & 3)) * 512);
    // ---- Y phase: 16 MFMAs (4 col-tiles x 4 k-frags) ----
    #pragma unroll
    for (int t2 = 0; t2 < 2; ++t2)
      #pragma unroll
      for (int kf = 0; kf < 4; ++kf)
        yacc[t2] = __builtin_amdgcn_mfma_f32_32x32x16_bf16(pf[kf], bt0[t2 * 4 + kf], yacc[t2], 0, 0, 0);
    #pragma unroll
    for (int t2 = 0; t2 < 2; ++t2)
      #pragma unroll
      for (int kf = 0; kf < 4; ++kf)
        yacc[2 + t2] = __builtin_amdgcn_mfma_f32_32x32x16_bf16(pf[kf], bt1[t2 * 4 + kf], yacc[2 + t2], 0, 0, 0);
  }

  // ---- epilogue: out flat at ob[n*256 + k'] ----
  #pragma unroll
  for (int ctile = 0; ctile < 4; ++ctile) {
    const int col = 128 * ct + 32 * ctile + l31;
    #pragma unroll
    for (int reg = 0; reg < 16; ++reg) {
      const int rowp = (reg & 3) + 8 * (reg >> 2) + 4 * h;
      ob[(size_t)(64 * nt + 32 * rt + rowp) * NC + col] = yacc[ctile][reg];
    }
  }
}

extern "C" void kernel_launch(void* const* d_in, const int* in_sizes, int n_in,
                              void* d_out, int out_size, void* d_ws, size_t ws_size,
                              hipStream_t stream) {
  const float* x    = (const float*)d_in[0];
  const float* W    = (const float*)d_in[1];
  const float* bias = (const float*)d_in[2];
  float* out = (float*)d_out;

  const size_t SZ = (size_t)NB * CHW * sizeof(unsigned short);  // 18,874,368 B
  double* partials       = (double*)d_ws;                        // 9216 B used
  unsigned short* wp     = (unsigned short*)((char*)d_ws + 16384);   // 128 KB
  unsigned short* x1p    = (unsigned short*)((char*)d_ws + 147456);
  unsigned short* xtp    = (unsigned short*)((char*)d_ws + 147456 + SZ);
  unsigned short* trflat = (unsigned short*)((char*)d_ws + 147456 + 2 * SZ);
  unsigned short* trp    = (unsigned short*)((char*)d_ws + 147456 + 3 * SZ);

  wpack_kernel<<<8, 256, 0, stream>>>(W, wp);
  x1pack_kernel<<<dim3(72, 16), 256, 0, stream>>>(x, x1p, partials);
  xtpack_kernel<<<dim3(36, 4, 16), 256, 0, stream>>>(x, xtp);
  conv_kernel<<<576, 256, 0, stream>>>(wp, bias, xtp, trflat);
  trpack_kernel<<<dim3(36, 2, 16), 256, 0, stream>>>(trflat, trp);
  fused_kernel<<<576, 256, 0, stream>>>(x1p, xtp, trp, partials, out);
}

// Round 8
// 293.102 us; speedup vs baseline: 1.2342x; 1.2342x over previous
//
#include <hip/hip_runtime.h>

#define NB 16
#define NC 256
#define HW 2304
#define CHW 589824  // NC*HW

typedef __attribute__((ext_vector_type(8))) short bf16x8;
typedef __attribute__((ext_vector_type(16))) float f32x16;

union BF8 { bf16x8 v; unsigned short u[8]; };

__device__ inline unsigned short f2bf(float f) {
  unsigned u = __builtin_bit_cast(unsigned, f);
  u += 0x7fffu + ((u >> 16) & 1u);  // RNE (inputs finite)
  return (unsigned short)(u >> 16);
}

// ================= K1: prep (wpack + x1pack + xtpack), role-switched =================
// wp[rt][f][l][j]      = W[32rt + (l&31)][16f + 8*(l>>5) + j]
// x1p[b][nb][f][l][j]  = v[(32nb + (l&31))*256 + 16f + 8*(l>>5) + j]   (+ sumsq partials)
// xtp[b][mb][f][l][j]  = x[b][k = 16f+8*(l>>5)+j][m = 32mb + (l&31)]
__global__ __launch_bounds__(256) void prep_kernel(const float* __restrict__ x,
                                                   const float* __restrict__ W,
                                                   unsigned short* __restrict__ wp,
                                                   unsigned short* __restrict__ x1p,
                                                   unsigned short* __restrict__ xtp,
                                                   double* __restrict__ partials) {
  __shared__ __align__(16) char smem[33344];
  const int bid = blockIdx.x;
  const int tid = threadIdx.x;

  if (bid < 8) {  // ---- wpack, rt = bid ----
    const int rt = bid;
    float* tile = (float*)smem;  // [32][260]
    const float4* src = (const float4*)(W + (size_t)rt * 32 * 256);
    #pragma unroll
    for (int it = 0; it < 8; ++it) {
      const int i = tid + 256 * it;
      float4 v = src[i];
      const int fi = 4 * i, row = fi >> 8, col = fi & 255;
      *(float4*)&tile[row * 260 + col] = v;
    }
    __syncthreads();
    const int w = tid >> 6, l = tid & 63, l31 = l & 31, h = l >> 5;
    unsigned short* dst = wp + (size_t)rt * 8192;
    #pragma unroll
    for (int ff = 0; ff < 4; ++ff) {
      const int f = 4 * w + ff;
      BF8 o;
      #pragma unroll
      for (int j = 0; j < 8; ++j)
        o.u[j] = f2bf(tile[l31 * 260 + 16 * f + 8 * h + j]);
      *(bf16x8*)(dst + (((size_t)f) * 64 + l) * 8) = o.v;
    }
  } else if (bid < 8 + 1152) {  // ---- x1pack + sumsq ----
    const int e = bid - 8;
    const int nb = e % 72, b = e / 72;
    float* tile = (float*)smem;              // [32][260]
    double* red = (double*)(smem + 33280);   // [4]
    const float4* src = (const float4*)(x + (size_t)b * CHW + nb * 8192);
    double ss = 0.0;
    #pragma unroll
    for (int it = 0; it < 8; ++it) {
      const int i = tid + 256 * it;
      float4 v = src[i];
      const int fi = 4 * i, row = fi >> 8, col = fi & 255;
      *(float4*)&tile[row * 260 + col] = v;
      ss += (double)v.x * v.x + (double)v.y * v.y + (double)v.z * v.z + (double)v.w * v.w;
    }
    #pragma unroll
    for (int off = 32; off > 0; off >>= 1) ss += __shfl_down(ss, off, 64);
    const int w = tid >> 6, l = tid & 63;
    if (l == 0) red[w] = ss;
    __syncthreads();
    if (tid == 0) partials[b * 72 + nb] = red[0] + red[1] + red[2] + red[3];
    const int l31 = l & 31, h = l >> 5;
    unsigned short* dst = x1p + (size_t)b * CHW + (size_t)nb * 8192;
    #pragma unroll
    for (int ff = 0; ff < 4; ++ff) {
      const int f = 4 * w + ff;
      BF8 o;
      #pragma unroll
      for (int j = 0; j < 8; ++j)
        o.u[j] = f2bf(tile[l31 * 260 + 16 * f + 8 * h + j]);
      *(bf16x8*)(dst + (((size_t)f) * 64 + l) * 8) = o.v;
    }
  } else {  // ---- xtpack ----
    const int e = bid - 1160;
    const int mt = e % 36, kt = (e / 36) % 4, b = e / 144;
    const int m0 = mt * 64, k0 = kt * 64;
    float* tile = (float*)smem;  // [64][68]
    const float* xb = x + (size_t)b * CHW;
    #pragma unroll
    for (int it = 0; it < 4; ++it) {
      const int i = tid + 256 * it;
      const int row = i >> 4, c4 = (i & 15) * 4;
      float4 v = *(const float4*)(xb + (size_t)(k0 + row) * HW + m0 + c4);
      *(float4*)&tile[row * 68 + c4] = v;
    }
    __syncthreads();
    const int w = tid >> 6, l = tid & 63, l31 = l & 31, h = l >> 5;
    unsigned short* dst = xtp + (size_t)b * CHW;
    #pragma unroll
    for (int pp = 0; pp < 2; ++pp) {
      const int p = 2 * w + pp, mbl = p >> 2, fl = p & 3;
      BF8 o;
      #pragma unroll
      for (int j = 0; j < 8; ++j)
        o.u[j] = f2bf(tile[(16 * fl + 8 * h + j) * 68 + 32 * mbl + l31]);
      const int mb = 2 * mt + mbl, f = 4 * kt + fl;
      *(bf16x8*)(dst + (((size_t)mb * 16 + f) * 64 + l) * 8) = o.v;
    }
  }
}

// ================= K2: conv (MFMA) -> trflat (c'-major bf16), + finish role =================
// trflat[c'][m] = sum_k W[c'][k]*x[b][k][m] + bias[c']   (R5-proven body)
__global__ __launch_bounds__(256, 2) void conv_kernel(const unsigned short* __restrict__ wp,
                                                      const float* __restrict__ bias,
                                                      const unsigned short* __restrict__ xtp,
                                                      unsigned short* __restrict__ trflat,
                                                      const double* __restrict__ partials,
                                                      float* __restrict__ inv_xn2) {
  const int bid = blockIdx.x;
  if (bid == 576) {  // ---- finish role: 1/xn^2 per batch (indep. of conv output) ----
    const int t = threadIdx.x;
    const int b = t >> 4, i0 = t & 15;
    double v = 0.0;
    for (int i = i0; i < 72; i += 16) v += partials[b * 72 + i];
    v += __shfl_down(v, 8, 64);
    v += __shfl_down(v, 4, 64);
    v += __shfl_down(v, 2, 64);
    v += __shfl_down(v, 1, 64);
    if (i0 == 0) inv_xn2[b] = (float)(1.0 / v);
    return;
  }
  const int xcd = bid & 7, j = bid >> 3;
  const int hi = (j >= 36) ? 1 : 0;
  const int b = xcd + 8 * hi;
  const int ch = j - 36 * hi;
  const int m0 = ch * 64;
  const int tid = threadIdx.x, w = tid >> 6, l = tid & 63, l31 = l & 31, h = l >> 5;
  const unsigned short* xb = xtp + (size_t)b * CHW;
  unsigned short* tb = trflat + (size_t)b * CHW;
  bf16x8 af[2][16];
  #pragma unroll
  for (int rb = 0; rb < 2; ++rb) {
    const int rt = w + 4 * rb;
    #pragma unroll
    for (int f = 0; f < 16; ++f)
      af[rb][f] = *(const bf16x8*)(wp + (((size_t)rt * 16 + f) * 64 + l) * 8);
  }
  f32x16 yacc[2][2];
  #pragma unroll
  for (int rb = 0; rb < 2; ++rb)
    #pragma unroll
    for (int cb = 0; cb < 2; ++cb)
      #pragma unroll
      for (int i = 0; i < 16; ++i) yacc[rb][cb][i] = 0.f;
  #pragma unroll 4
  for (int f = 0; f < 16; ++f) {
    #pragma unroll
    for (int cb = 0; cb < 2; ++cb) {
      const int mb = 2 * ch + cb;
      bf16x8 bv = *(const bf16x8*)(xb + (((size_t)mb * 16 + f) * 64 + l) * 8);
      yacc[0][cb] = __builtin_amdgcn_mfma_f32_32x32x16_bf16(af[0][f], bv, yacc[0][cb], 0, 0, 0);
      yacc[1][cb] = __builtin_amdgcn_mfma_f32_32x32x16_bf16(af[1][f], bv, yacc[1][cb], 0, 0, 0);
    }
  }
  #pragma unroll
  for (int rb = 0; rb < 2; ++rb)
    #pragma unroll
    for (int reg = 0; reg < 16; ++reg) {
      const int row = 32 * (w + 4 * rb) + (reg & 3) + 8 * (reg >> 2) + 4 * h;
      const float bv = bias[row];
      #pragma unroll
      for (int cb = 0; cb < 2; ++cb)
        tb[(size_t)row * HW + m0 + 32 * cb + l31] = f2bf(yacc[rb][cb][reg] + bv);
    }
}

// ================= K3: trpack — raw-reshape frag pack (R5-proven, linear read) =================
// trp[b][mb][cb8][kf][l][j] = trflat_flat[(64mb + 16kf + 8*(l>>5) + j)*256 + 32cb8 + (l&31)]
__global__ __launch_bounds__(256) void trpack_kernel(const unsigned short* __restrict__ trflat,
                                                     unsigned short* __restrict__ trp) {
  const int mb = blockIdx.x, half = blockIdx.y, b = blockIdx.z;
  const unsigned short* src = trflat + (size_t)b * CHW + (size_t)mb * 16384 + 128 * half;
  __shared__ unsigned short tile[64 * 136];
  const int tid = threadIdx.x;
  #pragma unroll
  for (int it = 0; it < 4; ++it) {
    const int i = tid + 256 * it;
    const int row = i >> 4, c8 = (i & 15) * 8;
    *(uint4*)&tile[row * 136 + c8] = *(const uint4*)(src + (size_t)row * 256 + c8);
  }
  __syncthreads();
  const int kf = tid >> 6, l = tid & 63, l31 = l & 31, h = l >> 5;
  unsigned short* dst = trp + (size_t)b * CHW + (size_t)mb * 16384;
  #pragma unroll
  for (int cl = 0; cl < 4; ++cl) {
    BF8 o;
    #pragma unroll
    for (int j = 0; j < 8; ++j)
      o.u[j] = tile[(16 * kf + 8 * h + j) * 136 + 32 * cl + l31];
    const int cb8 = 4 * half + cl;
    *(bf16x8*)(dst + (((size_t)cb8 * 4 + kf) * 64 + l) * 8) = o.v;
  }
}

// ================= K4: fused (R4 structure verbatim; LB(256,4) — pure residency hint at VGPR 68) =================
// n32 tiles, 1152 blocks, A-frags in LDS, chunk m=128, double-buffered P.
__global__ __launch_bounds__(256, 4) void fused_kernel(const unsigned short* __restrict__ x1p,
                                                       const unsigned short* __restrict__ xtp,
                                                       const unsigned short* __restrict__ trp,
                                                       const float* __restrict__ inv_xn2,
                                                       float* __restrict__ out) {
  const int bid = blockIdx.x;
  const int xcd = bid & 7, j = bid >> 3;     // j in [0,144)
  const int hi = (j >= 72) ? 1 : 0;
  const int b = xcd + 8 * hi;                // one batch per XCD at a time
  const int nt = j - 72 * hi;                // [0,72) n-tile of 32 rows
  const unsigned short* x1b = x1p + (size_t)b * CHW + (size_t)nt * 8192;
  const unsigned short* xtb = xtp + (size_t)b * CHW;
  const unsigned short* ttb = trp + (size_t)b * CHW;
  float* ob = out + (size_t)b * CHW;
  const float inv2 = inv_xn2[b];

  const int tid = threadIdx.x;
  const int c = tid >> 6, lane = tid & 63;   // wave c = S-col / Y-col group
  const int l31 = lane & 31, h = lane >> 5;

  __shared__ unsigned short Af[8192];        // 16 A-frags x 512 shorts (16 KB)
  __shared__ unsigned short Pl[2][32][136];  // double-buffered P

  {  // stage A-frags (coalesced 16B) into LDS once
    const uint4* gsrc = (const uint4*)x1b;
    uint4* ldst = (uint4*)Af;
    #pragma unroll
    for (int it = 0; it < 4; ++it) ldst[tid + 256 * it] = gsrc[tid + 256 * it];
  }
  __syncthreads();

  f32x16 yacc[2];
  #pragma unroll
  for (int cb = 0; cb < 2; ++cb)
    #pragma unroll
    for (int i = 0; i < 16; ++i) yacc[cb][i] = 0.f;

  for (int ch = 0; ch < 18; ++ch) {
    const int pb = ch & 1;
    // ---- S phase: two 8-MFMA chains, A from LDS ----
    const unsigned short* bp = xtb + ((size_t)(4 * ch + c) * 16) * 512 + lane * 8;
    bf16x8 b0[8], b1[8];
    #pragma unroll
    for (int f = 0; f < 8; ++f) b0[f] = *(const bf16x8*)(bp + f * 512);
    #pragma unroll
    for (int f = 0; f < 8; ++f) b1[f] = *(const bf16x8*)(bp + (f + 8) * 512);
    f32x16 s0, s1;
    #pragma unroll
    for (int i = 0; i < 16; ++i) { s0[i] = 0.f; s1[i] = 0.f; }
    #pragma unroll
    for (int f = 0; f < 8; ++f) {
      bf16x8 a0 = *(const bf16x8*)(Af + f * 512 + lane * 8);
      s0 = __builtin_amdgcn_mfma_f32_32x32x16_bf16(a0, b0[f], s0, 0, 0, 0);
    }
    #pragma unroll
    for (int f = 0; f < 8; ++f) {
      bf16x8 a1 = *(const bf16x8*)(Af + (f + 8) * 512 + lane * 8);
      s1 = __builtin_amdgcn_mfma_f32_32x32x16_bf16(a1, b1[f], s1, 0, 0, 0);
    }
    // ---- prefetch Y B-frags for cb=0 ----
    bf16x8 bt0[8];
    #pragma unroll
    for (int kk = 0; kk < 8; ++kk) {
      const size_t mb = 2 * ch + (kk >> 2);
      bt0[kk] = *(const bf16x8*)(ttb + mb * 16384 + ((size_t)((2 * c) * 4 + (kk & 3))) * 512 + lane * 8);
    }
    // ---- P = relu((s0+s1)*inv2)^2 -> bf16 -> LDS ----
    #pragma unroll
    for (int reg = 0; reg < 16; ++reg) {
      const int rowp = (reg & 3) + 8 * (reg >> 2) + 4 * h;
      float v = (s0[reg] + s1[reg]) * inv2;
      v = fmaxf(v, 0.f);
      v *= v;
      Pl[pb][rowp][32 * c + l31] = f2bf(v);
    }
    __syncthreads();  // single barrier per chunk (double-buffered P)
    // ---- P A-frags + cb=1 B-frags ----
    bf16x8 pf[8];
    #pragma unroll
    for (int kk = 0; kk < 8; ++kk)
      pf[kk] = *(const bf16x8*)&Pl[pb][l31][16 * kk + 8 * h];
    bf16x8 bt1[8];
    #pragma unroll
    for (int kk = 0; kk < 8; ++kk) {
      const size_t mb = 2 * ch + (kk >> 2);
      bt1[kk] = *(const bf16x8*)(ttb + mb * 16384 + ((size_t)((2 * c + 1) * 4 + (kk & 3))) * 512 + lane * 8);
    }
    // ---- Y phase: 16 MFMAs, two independent chains ----
    #pragma unroll
    for (int kk = 0; kk < 8; ++kk)
      yacc[0] = __builtin_amdgcn_mfma_f32_32x32x16_bf16(pf[kk], bt0[kk], yacc[0], 0, 0, 0);
    #pragma unroll
    for (int kk = 0; kk < 8; ++kk)
      yacc[1] = __builtin_amdgcn_mfma_f32_32x32x16_bf16(pf[kk], bt1[kk], yacc[1], 0, 0, 0);
  }

  // ---- epilogue: out flat at ob[n*256 + k'] ----
  #pragma unroll
  for (int cb = 0; cb < 2; ++cb) {
    const int col = 64 * c + 32 * cb + l31;
    #pragma unroll
    for (int reg = 0; reg < 16; ++reg) {
      const int rowp = (reg & 3) + 8 * (reg >> 2) + 4 * h;
      ob[(size_t)(32 * nt + rowp) * NC + col] = yacc[cb][reg];
    }
  }
}

extern "C" void kernel_launch(void* const* d_in, const int* in_sizes, int n_in,
                              void* d_out, int out_size, void* d_ws, size_t ws_size,
                              hipStream_t stream) {
  const float* x    = (const float*)d_in[0];
  const float* W    = (const float*)d_in[1];
  const float* bias = (const float*)d_in[2];
  float* out = (float*)d_out;

  const size_t SZ = (size_t)NB * CHW * sizeof(unsigned short);  // 18,874,368 B
  double* partials       = (double*)d_ws;                           // 9216 B used
  float* inv_xn2         = (float*)((char*)d_ws + 16384);
  unsigned short* wp     = (unsigned short*)((char*)d_ws + 32768);  // 128 KB
  unsigned short* x1p    = (unsigned short*)((char*)d_ws + 163840);
  unsigned short* xtp    = (unsigned short*)((char*)d_ws + 163840 + SZ);
  unsigned short* trflat = (unsigned short*)((char*)d_ws + 163840 + 2 * SZ);
  unsigned short* trp    = (unsigned short*)((char*)d_ws + 163840 + 3 * SZ);

  prep_kernel<<<3464, 256, 0, stream>>>(x, W, wp, x1p, xtp, partials);
  conv_kernel<<<577, 256, 0, stream>>>(wp, bias, xtp, trflat, partials, inv_xn2);
  trpack_kernel<<<dim3(36, 2, 16), 256, 0, stream>>>(trflat, trp);
  fused_kernel<<<1152, 256, 0, stream>>>(x1p, xtp, trp, inv_xn2, out);
}